// Round 1
// baseline (802.830 us; speedup 1.0000x reference)
//
#include <hip/hip_runtime.h>
#include <cstdint>
#include <cstddef>

// SwinBlock3D: LN1 -> roll(-1,-3,-3) -> window(2,7,7) attn (12 heads, rel-bias)
// -> proj + resid -> LN2 -> MLP(384->1536 gelu ->384) + resid.
// bf16 MFMA for all matmuls, fp32 LN/softmax/residuals.

typedef __bf16 bf16x8 __attribute__((ext_vector_type(8)));
typedef float f32x4 __attribute__((ext_vector_type(4)));

#define DIM 384
#define QKV_DIM 1152
#define HID 1536
#define NHEADS 12
#define NTOK 50176
#define NWIN 512

// ---------------- prep kernels ----------------
__global__ __launch_bounds__(256) void build_tokmap_k(int* __restrict__ map) {
  int t = blockIdx.x * 256 + threadIdx.x;
  if (t >= NTOK) return;
  int win = t / 98, n = t - win * 98;
  int b = win >> 8, tw = (win >> 6) & 3, hw = (win >> 3) & 7, ww = win & 7;
  int dt = n / 49; int rem = n - dt * 49; int dh = rem / 7, dw = rem - dh * 7;
  int t0 = (tw * 2 + dt + 1) & 7;                 // roll by shift (1,3,3)
  int h0 = hw * 7 + dh + 3; if (h0 >= 56) h0 -= 56;
  int w0 = ww * 7 + dw + 3; if (w0 >= 56) w0 -= 56;
  map[t] = ((b * 8 + t0) * 56 + h0) * 56 + w0;    // spatial row for window-token t
}

__global__ __launch_bounds__(256) void expand_bias_k(const float* __restrict__ table,
                                                     const int* __restrict__ rel,
                                                     float* __restrict__ out) {
  int e = blockIdx.x * 256 + threadIdx.x;
  if (e >= NHEADS * 9604) return;
  int h = e / 9604, r = e - h * 9604;
  out[e] = table[rel[r] * NHEADS + h];            // [h][i][j]
}

__global__ __launch_bounds__(256) void transpose_w_k(const float* __restrict__ W,
                                                     __bf16* __restrict__ WT,
                                                     int K, int N, int scaleCols, float scale) {
  int e = blockIdx.x * 256 + threadIdx.x;
  if (e >= K * N) return;
  int n = e / K, k = e - n * K;
  float v = W[(size_t)k * N + n];
  if (n < scaleCols) v *= scale;                  // fold q-scale into W_q
  WT[e] = (__bf16)v;                              // WT[n][k]
}

__global__ __launch_bounds__(256) void scale_bias_k(const float* __restrict__ b,
                                                    float* __restrict__ out,
                                                    int n, int scaleCols, float scale) {
  int e = blockIdx.x * 256 + threadIdx.x;
  if (e >= n) return;
  out[e] = b[e] * (e < scaleCols ? scale : 1.0f);
}

// ---------------- layernorm (1 wave per token row of 384) ----------------
__global__ __launch_bounds__(256) void ln_k(const float* __restrict__ x,
                                            const float* __restrict__ g,
                                            const float* __restrict__ bta,
                                            __bf16* __restrict__ out,
                                            const int* __restrict__ map) {
  int w = threadIdx.x >> 6, l = threadIdx.x & 63;
  int tok = blockIdx.x * 4 + w;
  int src = map ? map[tok] : tok;
  const float* row = x + (size_t)src * DIM;
  float v[6]; float s = 0.f;
  #pragma unroll
  for (int j = 0; j < 6; ++j) { v[j] = row[l + 64 * j]; s += v[j]; }
  #pragma unroll
  for (int m = 1; m < 64; m <<= 1) s += __shfl_xor(s, m, 64);
  float mu = s * (1.f / DIM);
  float var = 0.f;
  #pragma unroll
  for (int j = 0; j < 6; ++j) { float d = v[j] - mu; var += d * d; }
  #pragma unroll
  for (int m = 1; m < 64; m <<= 1) var += __shfl_xor(var, m, 64);
  float rs = rsqrtf(var * (1.f / DIM) + 1e-5f);
  __bf16* orow = out + (size_t)tok * DIM;
  #pragma unroll
  for (int j = 0; j < 6; ++j) {
    int c = l + 64 * j;
    orow[c] = (__bf16)((v[j] - mu) * rs * g[c] + bta[c]);
  }
}

// ---------------- 128x128 bf16 MFMA GEMM, BK=64, 4 waves ----------------
// A[M][K] bf16 row-major, BT[N][K] bf16 row-major. C = A @ BT^T.
// LDS XOR-swizzled (chunk ^= row&7) so ds_read_b128 frag loads are balanced.
// EPI: 0 = +bias -> bf16   1 = +bias, scatter via tokmap, +resid -> fp32
//      2 = +bias, gelu -> bf16   3 = +bias, +resid -> fp32 (linear)
template <int EPI>
__global__ __launch_bounds__(256) void gemm_k(const __bf16* __restrict__ A,
                                              const __bf16* __restrict__ BT,
                                              const float* __restrict__ bias,
                                              int M, int N, int K,
                                              __bf16* __restrict__ outb,
                                              float* __restrict__ outf,
                                              const float* __restrict__ resid,
                                              const int* __restrict__ tokmap) {
  __shared__ __align__(1024) char lds[32768];
  char* sA = lds;
  char* sB = lds + 16384;
  const int tid = threadIdx.x;
  const int l = tid & 63, w = tid >> 6;
  const int lr = l & 15, lg = l >> 4;
  const int ntile = N >> 7;
  const int bm = blockIdx.x / ntile, bn = blockIdx.x - bm * ntile;
  const int m0 = bm << 7, n0 = bn << 7;
  const int wr = w >> 1, wc = w & 1;
  const int srow = (w << 5) + (l >> 3);             // staging row (+ i*8)
  const int schunk = (l & 7) << 3;                  // element k-offset of 16B chunk
  const int sphys = ((l & 7) ^ (l >> 3)) << 4;      // swizzled byte offset in row

  f32x4 acc[4][4] = {};
  const int nk = K >> 6;
  bf16x8 ra[4], rb[4];
  #pragma unroll
  for (int i = 0; i < 4; ++i) {
    int row = srow + (i << 3);
    ra[i] = *(const bf16x8*)(A + (size_t)(m0 + row) * K + schunk);
    rb[i] = *(const bf16x8*)(BT + (size_t)(n0 + row) * K + schunk);
  }
  for (int kt = 0; kt < nk; ++kt) {
    __syncthreads();
    #pragma unroll
    for (int i = 0; i < 4; ++i) {
      int row = srow + (i << 3);
      *(bf16x8*)(sA + (row << 7) + sphys) = ra[i];
      *(bf16x8*)(sB + (row << 7) + sphys) = rb[i];
    }
    __syncthreads();
    if (kt + 1 < nk) {                               // prefetch next tile under MFMA
      int k0 = (kt + 1) << 6;
      #pragma unroll
      for (int i = 0; i < 4; ++i) {
        int row = srow + (i << 3);
        ra[i] = *(const bf16x8*)(A + (size_t)(m0 + row) * K + k0 + schunk);
        rb[i] = *(const bf16x8*)(BT + (size_t)(n0 + row) * K + k0 + schunk);
      }
    }
    #pragma unroll
    for (int kk = 0; kk < 2; ++kk) {
      bf16x8 af[4], bfv[4];
      const int ck = (kk << 2) + lg;
      #pragma unroll
      for (int m = 0; m < 4; ++m) {
        int r = (wr << 6) + (m << 4) + lr;
        af[m] = *(const bf16x8*)(sA + (r << 7) + ((ck ^ (r & 7)) << 4));
      }
      #pragma unroll
      for (int n = 0; n < 4; ++n) {
        int r = (wc << 6) + (n << 4) + lr;
        bfv[n] = *(const bf16x8*)(sB + (r << 7) + ((ck ^ (r & 7)) << 4));
      }
      #pragma unroll
      for (int m = 0; m < 4; ++m)
        #pragma unroll
        for (int n = 0; n < 4; ++n)
          acc[m][n] = __builtin_amdgcn_mfma_f32_16x16x32_bf16(af[m], bfv[n], acc[m][n], 0, 0, 0);
    }
  }
  // epilogue: C row = (lane>>4)*4 + reg, col = lane&15  [verified layout]
  #pragma unroll
  for (int m = 0; m < 4; ++m) {
    int gm0 = m0 + (wr << 6) + (m << 4) + (lg << 2);
    #pragma unroll
    for (int n = 0; n < 4; ++n) {
      int gn = n0 + (wc << 6) + (n << 4) + lr;
      f32x4 a = acc[m][n];
      float bb = bias[gn];
      if (EPI == 0) {
        #pragma unroll
        for (int r = 0; r < 4; ++r)
          outb[(size_t)(gm0 + r) * N + gn] = (__bf16)(a[r] + bb);
      } else if (EPI == 1) {
        #pragma unroll
        for (int r = 0; r < 4; ++r) {
          int dst = tokmap[gm0 + r];
          size_t idx = (size_t)dst * DIM + gn;
          outf[idx] = resid[idx] + a[r] + bb;
        }
      } else if (EPI == 2) {
        #pragma unroll
        for (int r = 0; r < 4; ++r) {
          float vv = a[r] + bb;
          outb[(size_t)(gm0 + r) * N + gn] =
              (__bf16)(0.5f * vv * (1.0f + erff(vv * 0.70710678118654752f)));
        }
      } else {
        #pragma unroll
        for (int r = 0; r < 4; ++r) {
          size_t idx = (size_t)(gm0 + r) * N + gn;
          outf[idx] = resid[idx] + a[r] + bb;
        }
      }
    }
  }
}

// ---------------- window attention: 1 wave per (window, head) ----------------
// N=98 padded to 112 (7x16 frags). S=QK^T via MFMA straight from global qkv,
// in-register softmax (16-lane shfl), P->LDS bf16 (swizzled), PV via MFMA with
// V^T staged in LDS. Pad cols masked to -1e30; pad k-range zeroed once.
__global__ __launch_bounds__(64) void attn_k(const __bf16* __restrict__ qkv,
                                             const float* __restrict__ bias_exp,
                                             __bf16* __restrict__ out) {
  __shared__ __align__(1024) char smem[112 * 256 + 32 * 256];
  char* P = smem;                 // [112 rows][256B = 128 bf16 cols], swizzled
  char* VT = smem + 112 * 256;    // [32 d][256B = 128 toks], swizzled
  const int l = threadIdx.x;
  const int win = blockIdx.x / NHEADS, h = blockIdx.x - win * NHEADS;
  const int lr = l & 15, lg = l >> 4;
  const size_t wbase = (size_t)win * 98 * QKV_DIM;
  const f32x4 fz = {};
  const bf16x8 z8 = {};

  // zero pad regions: P cols 112..127 (chunks 14,15), VT toks 96..127 (chunks 12..15)
  #pragma unroll
  for (int it = 0; it < 4; ++it) {
    int id = it * 64 + l;
    int row = id >> 1, c = 14 + (id & 1);
    if (row < 112) *(f32x4*)(P + row * 256 + ((c ^ (row & 7)) << 4)) = fz;
  }
  #pragma unroll
  for (int it = 0; it < 2; ++it) {
    int id = it * 64 + l;
    int d = id >> 2, c = 12 + (id & 3);
    *(f32x4*)(VT + d * 256 + ((c ^ (d & 7)) << 4)) = fz;
  }
  __syncthreads();

  // stage V^T: V[tok][d] -> VT[d][tok]
  const __bf16* vbase = qkv + wbase + 768 + h * 32;
  #pragma unroll
  for (int it = 0; it < 7; ++it) {
    int id = it * 64 + l;
    if (id < 392) {
      int tok = id >> 2, dc = id & 3;
      bf16x8 vv = *(const bf16x8*)(vbase + (size_t)tok * QKV_DIM + dc * 8);
      #pragma unroll
      for (int e = 0; e < 8; ++e) {
        int d = dc * 8 + e;
        *(__bf16*)(VT + d * 256 + (((tok >> 3) ^ (d & 7)) << 4) + ((tok & 7) << 1)) = vv[e];
      }
    }
  }

  // K b-frags (K^T operand): lane holds tok = ni*16+lr, d = lg*8..+8
  const __bf16* kbase = qkv + wbase + 384 + h * 32;
  const __bf16* qbase = qkv + wbase + h * 32;
  bf16x8 kf[7];
  #pragma unroll
  for (int ni = 0; ni < 7; ++ni) {
    int tok = ni * 16 + lr;
    kf[ni] = (tok < 98) ? *(const bf16x8*)(kbase + (size_t)tok * QKV_DIM + lg * 8) : z8;
  }
  const float* bh = bias_exp + h * 9604;

  for (int mi = 0; mi < 7; ++mi) {
    int qt = mi * 16 + lr;
    bf16x8 qf = (qt < 98) ? *(const bf16x8*)(qbase + (size_t)qt * QKV_DIM + lg * 8) : z8;
    f32x4 s[7];
    #pragma unroll
    for (int ni = 0; ni < 7; ++ni)
      s[ni] = __builtin_amdgcn_mfma_f32_16x16x32_bf16(qf, kf[ni], fz, 0, 0, 0);
    int i0 = mi * 16 + lg * 4;
    #pragma unroll
    for (int r = 0; r < 4; ++r) {
      int i = i0 + r;
      float mx = -1e30f;
      #pragma unroll
      for (int ni = 0; ni < 7; ++ni) {
        int j = ni * 16 + lr;
        float vv = s[ni][r];
        if (j < 98) { if (i < 98) vv += bh[i * 98 + j]; }
        else vv = -1e30f;
        s[ni][r] = vv;
        mx = fmaxf(mx, vv);
      }
      #pragma unroll
      for (int m = 1; m < 16; m <<= 1) mx = fmaxf(mx, __shfl_xor(mx, m, 64));
      float sum = 0.f;
      #pragma unroll
      for (int ni = 0; ni < 7; ++ni) { float p = __expf(s[ni][r] - mx); s[ni][r] = p; sum += p; }
      #pragma unroll
      for (int m = 1; m < 16; m <<= 1) sum += __shfl_xor(sum, m, 64);
      float inv = 1.0f / sum;
      #pragma unroll
      for (int ni = 0; ni < 7; ++ni) {
        int j = ni * 16 + lr;
        *(__bf16*)(P + i * 256 + (((j >> 3) ^ (i & 7)) << 4) + ((j & 7) << 1)) =
            (__bf16)(s[ni][r] * inv);
      }
    }
  }
  __syncthreads();

  // PV: A = P rows (i), K = tok j (pad 128), B = V (VT rows)
  bf16x8 vbf[2][4];
  #pragma unroll
  for (int nf = 0; nf < 2; ++nf) {
    int d = nf * 16 + lr;
    #pragma unroll
    for (int ks = 0; ks < 4; ++ks) {
      int ck = ks * 4 + lg;
      vbf[nf][ks] = *(const bf16x8*)(VT + d * 256 + ((ck ^ (d & 7)) << 4));
    }
  }
  __bf16* obase = out + (size_t)win * 98 * DIM + h * 32;
  for (int mi = 0; mi < 7; ++mi) {
    int prow = mi * 16 + lr;
    bf16x8 pa[4];
    #pragma unroll
    for (int ks = 0; ks < 4; ++ks) {
      int ck = ks * 4 + lg;
      pa[ks] = *(const bf16x8*)(P + prow * 256 + ((ck ^ (prow & 7)) << 4));
    }
    #pragma unroll
    for (int nf = 0; nf < 2; ++nf) {
      f32x4 o = {};
      #pragma unroll
      for (int ks = 0; ks < 4; ++ks)
        o = __builtin_amdgcn_mfma_f32_16x16x32_bf16(pa[ks], vbf[nf][ks], o, 0, 0, 0);
      #pragma unroll
      for (int r = 0; r < 4; ++r) {
        int i = mi * 16 + lg * 4 + r;
        if (i < 98) obase[(size_t)i * DIM + nf * 16 + lr] = (__bf16)o[r];
      }
    }
  }
}

// ---------------- launch ----------------
extern "C" void kernel_launch(void* const* d_in, const int* in_sizes, int n_in,
                              void* d_out, int out_size, void* d_ws, size_t ws_size,
                              hipStream_t stream) {
  const float* x      = (const float*)d_in[0];
  const float* n1g    = (const float*)d_in[1];
  const float* n1b    = (const float*)d_in[2];
  const float* qkv_w  = (const float*)d_in[3];
  const float* qkv_b  = (const float*)d_in[4];
  const float* proj_w = (const float*)d_in[5];
  const float* proj_b = (const float*)d_in[6];
  const float* btab   = (const float*)d_in[7];
  const float* n2g    = (const float*)d_in[8];
  const float* n2b    = (const float*)d_in[9];
  const float* fc1_w  = (const float*)d_in[10];
  const float* fc1_b  = (const float*)d_in[11];
  const float* fc2_w  = (const float*)d_in[12];
  const float* fc2_b  = (const float*)d_in[13];
  const int*   relidx = (const int*)d_in[14];
  float* outp = (float*)d_out;
  (void)in_sizes; (void)n_in; (void)out_size; (void)ws_size;

  char* ws = (char*)d_ws;
  size_t off = 0;
  auto alloc = [&](size_t bytes) {
    char* p = ws + off;
    off = (off + bytes + 255) & ~(size_t)255;
    return p;
  };
  int*    tokmap = (int*)alloc((size_t)NTOK * 4);
  float*  biasex = (float*)alloc((size_t)NHEADS * 9604 * 4);
  __bf16* wqkvT  = (__bf16*)alloc((size_t)QKV_DIM * DIM * 2);
  __bf16* wprojT = (__bf16*)alloc((size_t)DIM * DIM * 2);
  __bf16* wfc1T  = (__bf16*)alloc((size_t)HID * DIM * 2);
  __bf16* wfc2T  = (__bf16*)alloc((size_t)DIM * HID * 2);
  float*  qkvbS  = (float*)alloc((size_t)QKV_DIM * 4);
  __bf16* tokens = (__bf16*)alloc((size_t)NTOK * DIM * 2);   // LN1 out / attn out / LN2 out
  __bf16* qkvbuf = (__bf16*)alloc((size_t)NTOK * HID * 2);   // qkv (1152) then h1 (1536)
  __bf16* attnout = tokens;
  __bf16* h1 = qkvbuf;

  const float scale = 0.17677669529663687f;  // 1/sqrt(32)

  build_tokmap_k<<<NTOK / 256, 256, 0, stream>>>(tokmap);
  expand_bias_k<<<(NHEADS * 9604 + 255) / 256, 256, 0, stream>>>(btab, relidx, biasex);
  transpose_w_k<<<(DIM * QKV_DIM) / 256, 256, 0, stream>>>(qkv_w, wqkvT, DIM, QKV_DIM, DIM, scale);
  transpose_w_k<<<(DIM * DIM) / 256, 256, 0, stream>>>(proj_w, wprojT, DIM, DIM, 0, 1.0f);
  transpose_w_k<<<(DIM * HID) / 256, 256, 0, stream>>>(fc1_w, wfc1T, DIM, HID, 0, 1.0f);
  transpose_w_k<<<(HID * DIM) / 256, 256, 0, stream>>>(fc2_w, wfc2T, HID, DIM, 0, 1.0f);
  scale_bias_k<<<(QKV_DIM + 255) / 256, 256, 0, stream>>>(qkv_b, qkvbS, QKV_DIM, DIM, scale);

  ln_k<<<NTOK / 4, 256, 0, stream>>>(x, n1g, n1b, tokens, tokmap);
  gemm_k<0><<<(NTOK / 128) * (QKV_DIM / 128), 256, 0, stream>>>(
      tokens, wqkvT, qkvbS, NTOK, QKV_DIM, DIM, qkvbuf, nullptr, nullptr, nullptr);
  attn_k<<<NWIN * NHEADS, 64, 0, stream>>>(qkvbuf, biasex, attnout);
  gemm_k<1><<<(NTOK / 128) * (DIM / 128), 256, 0, stream>>>(
      attnout, wprojT, proj_b, NTOK, DIM, DIM, nullptr, outp, x, tokmap);
  ln_k<<<NTOK / 4, 256, 0, stream>>>(outp, n2g, n2b, tokens, nullptr);
  gemm_k<2><<<(NTOK / 128) * (HID / 128), 256, 0, stream>>>(
      tokens, wfc1T, fc1_b, NTOK, HID, DIM, h1, nullptr, nullptr, nullptr);
  gemm_k<3><<<(NTOK / 128) * (DIM / 128), 256, 0, stream>>>(
      h1, wfc2T, fc2_b, NTOK, DIM, HID, nullptr, outp, outp, nullptr);
}

// Round 2
// 522.901 us; speedup vs baseline: 1.5353x; 1.5353x over previous
//
#include <hip/hip_runtime.h>
#include <cstdint>
#include <cstddef>

// SwinBlock3D: LN1 -> roll(-1,-3,-3) -> window(2,7,7) attn (12 heads, rel-bias)
// -> proj + resid -> LN2 -> MLP(384->1536 gelu ->384) + resid.
// bf16 MFMA for all matmuls, fp32 LN/softmax/residuals.

typedef __bf16 bf16x8 __attribute__((ext_vector_type(8)));
typedef float f32x4 __attribute__((ext_vector_type(4)));

#define DIM 384
#define QKV_DIM 1152
#define HID 1536
#define NHEADS 12
#define NTOK 50176
#define NWIN 512

// ---------------- prep kernels ----------------
__global__ __launch_bounds__(256) void build_tokmap_k(int* __restrict__ map) {
  int t = blockIdx.x * 256 + threadIdx.x;
  if (t >= NTOK) return;
  int win = t / 98, n = t - win * 98;
  int b = win >> 8, tw = (win >> 6) & 3, hw = (win >> 3) & 7, ww = win & 7;
  int dt = n / 49; int rem = n - dt * 49; int dh = rem / 7, dw = rem - dh * 7;
  int t0 = (tw * 2 + dt + 1) & 7;                 // roll by shift (1,3,3)
  int h0 = hw * 7 + dh + 3; if (h0 >= 56) h0 -= 56;
  int w0 = ww * 7 + dw + 3; if (w0 >= 56) w0 -= 56;
  map[t] = ((b * 8 + t0) * 56 + h0) * 56 + w0;    // spatial row for window-token t
}

// packed bias in MFMA-fragment order: pb[h][mi][ni][lane][r], j>=98 mask pre-baked
__global__ __launch_bounds__(256) void expand_biasp_k(const float* __restrict__ table,
                                                      const int* __restrict__ rel,
                                                      float* __restrict__ out) {
  int e = blockIdx.x * 256 + threadIdx.x;
  if (e >= NHEADS * 49 * 256) return;
  int r = e & 3, l = (e >> 2) & 63;
  int rest = e >> 8;
  int ni = rest % 7, mi = (rest / 7) % 7, h = rest / 49;
  int i = mi * 16 + (l >> 4) * 4 + r;
  int j = ni * 16 + (l & 15);
  float v;
  if (j >= 98) v = -1e30f;          // pad-column mask baked in
  else if (i >= 98) v = 0.f;
  else v = table[rel[i * 98 + j] * NHEADS + h];
  out[e] = v;
}

__global__ __launch_bounds__(256) void transpose_w_k(const float* __restrict__ W,
                                                     __bf16* __restrict__ WT,
                                                     int K, int N, int scaleCols, float scale) {
  int e = blockIdx.x * 256 + threadIdx.x;
  if (e >= K * N) return;
  int n = e / K, k = e - n * K;
  float v = W[(size_t)k * N + n];
  if (n < scaleCols) v *= scale;                  // fold q-scale into W_q
  WT[e] = (__bf16)v;                              // WT[n][k]
}

__global__ __launch_bounds__(256) void scale_bias_k(const float* __restrict__ b,
                                                    float* __restrict__ out,
                                                    int n, int scaleCols, float scale) {
  int e = blockIdx.x * 256 + threadIdx.x;
  if (e >= n) return;
  out[e] = b[e] * (e < scaleCols ? scale : 1.0f);
}

// V^T: vt[(win*12+h)*32 + d][tok 0..127] bf16, zeros past tok 97
__global__ __launch_bounds__(384) void vtrans_k(const __bf16* __restrict__ qkv,
                                                __bf16* __restrict__ vt) {
  int win = blockIdx.x, t = threadIdx.x;          // t = h*32+d
  const __bf16* base = qkv + (size_t)win * 98 * QKV_DIM + 768 + t;
  __bf16* orow = vt + ((size_t)win * 384 + t) * 128;
  #pragma unroll
  for (int c = 0; c < 16; ++c) {
    bf16x8 pk;
    #pragma unroll
    for (int e2 = 0; e2 < 8; ++e2) {
      int tok = c * 8 + e2;
      pk[e2] = (tok < 98) ? base[(size_t)tok * QKV_DIM] : (__bf16)0.f;
    }
    *(bf16x8*)(orow + c * 8) = pk;
  }
}

// ---------------- layernorm (1 wave per token row of 384) ----------------
__global__ __launch_bounds__(256) void ln_k(const float* __restrict__ x,
                                            const float* __restrict__ g,
                                            const float* __restrict__ bta,
                                            __bf16* __restrict__ out,
                                            const int* __restrict__ map) {
  int w = threadIdx.x >> 6, l = threadIdx.x & 63;
  int tok = blockIdx.x * 4 + w;
  int src = map ? map[tok] : tok;
  const float* row = x + (size_t)src * DIM;
  float v[6]; float s = 0.f;
  #pragma unroll
  for (int j = 0; j < 6; ++j) { v[j] = row[l + 64 * j]; s += v[j]; }
  #pragma unroll
  for (int m = 1; m < 64; m <<= 1) s += __shfl_xor(s, m, 64);
  float mu = s * (1.f / DIM);
  float var = 0.f;
  #pragma unroll
  for (int j = 0; j < 6; ++j) { float d = v[j] - mu; var += d * d; }
  #pragma unroll
  for (int m = 1; m < 64; m <<= 1) var += __shfl_xor(var, m, 64);
  float rs = rsqrtf(var * (1.f / DIM) + 1e-5f);
  __bf16* orow = out + (size_t)tok * DIM;
  #pragma unroll
  for (int j = 0; j < 6; ++j) {
    int c = l + 64 * j;
    orow[c] = (__bf16)((v[j] - mu) * rs * g[c] + bta[c]);
  }
}

// ---------------- 128x128 bf16 MFMA GEMM, BK=64, 4 waves ----------------
// A[M][K] bf16 row-major, BT[N][K] bf16 row-major. C = A @ BT^T.
// EPI: 0 = +bias -> bf16   1 = +bias, scatter via tokmap, +resid -> fp32
//      2 = +bias, gelu -> bf16   3 = +bias, +resid -> fp32 (linear)
template <int EPI>
__global__ __launch_bounds__(256) void gemm_k(const __bf16* __restrict__ A,
                                              const __bf16* __restrict__ BT,
                                              const float* __restrict__ bias,
                                              int M, int N, int K,
                                              __bf16* __restrict__ outb,
                                              float* __restrict__ outf,
                                              const float* __restrict__ resid,
                                              const int* __restrict__ tokmap) {
  __shared__ __align__(1024) char lds[32768];
  char* sA = lds;
  char* sB = lds + 16384;
  const int tid = threadIdx.x;
  const int l = tid & 63, w = tid >> 6;
  const int lr = l & 15, lg = l >> 4;
  const int ntile = N >> 7;
  const int bm = blockIdx.x / ntile, bn = blockIdx.x - bm * ntile;
  const int m0 = bm << 7, n0 = bn << 7;
  const int wr = w >> 1, wc = w & 1;
  const int srow = (w << 5) + (l >> 3);             // staging row (+ i*8)
  const int schunk = (l & 7) << 3;                  // element k-offset of 16B chunk
  const int sphys = ((l & 7) ^ (l >> 3)) << 4;      // swizzled byte offset in row

  f32x4 acc[4][4] = {};
  const int nk = K >> 6;
  bf16x8 ra[4], rb[4];
  #pragma unroll
  for (int i = 0; i < 4; ++i) {
    int row = srow + (i << 3);
    ra[i] = *(const bf16x8*)(A + (size_t)(m0 + row) * K + schunk);
    rb[i] = *(const bf16x8*)(BT + (size_t)(n0 + row) * K + schunk);
  }
  for (int kt = 0; kt < nk; ++kt) {
    __syncthreads();
    #pragma unroll
    for (int i = 0; i < 4; ++i) {
      int row = srow + (i << 3);
      *(bf16x8*)(sA + (row << 7) + sphys) = ra[i];
      *(bf16x8*)(sB + (row << 7) + sphys) = rb[i];
    }
    __syncthreads();
    if (kt + 1 < nk) {                               // prefetch next tile under MFMA
      int k0 = (kt + 1) << 6;
      #pragma unroll
      for (int i = 0; i < 4; ++i) {
        int row = srow + (i << 3);
        ra[i] = *(const bf16x8*)(A + (size_t)(m0 + row) * K + k0 + schunk);
        rb[i] = *(const bf16x8*)(BT + (size_t)(n0 + row) * K + k0 + schunk);
      }
    }
    #pragma unroll
    for (int kk = 0; kk < 2; ++kk) {
      bf16x8 af[4], bfv[4];
      const int ck = (kk << 2) + lg;
      #pragma unroll
      for (int m = 0; m < 4; ++m) {
        int r = (wr << 6) + (m << 4) + lr;
        af[m] = *(const bf16x8*)(sA + (r << 7) + ((ck ^ (r & 7)) << 4));
      }
      #pragma unroll
      for (int n = 0; n < 4; ++n) {
        int r = (wc << 6) + (n << 4) + lr;
        bfv[n] = *(const bf16x8*)(sB + (r << 7) + ((ck ^ (r & 7)) << 4));
      }
      #pragma unroll
      for (int m = 0; m < 4; ++m)
        #pragma unroll
        for (int n = 0; n < 4; ++n)
          acc[m][n] = __builtin_amdgcn_mfma_f32_16x16x32_bf16(af[m], bfv[n], acc[m][n], 0, 0, 0);
    }
  }
  // epilogue: C row = (lane>>4)*4 + reg, col = lane&15
  #pragma unroll
  for (int m = 0; m < 4; ++m) {
    int gm0 = m0 + (wr << 6) + (m << 4) + (lg << 2);
    #pragma unroll
    for (int n = 0; n < 4; ++n) {
      int gn = n0 + (wc << 6) + (n << 4) + lr;
      f32x4 a = acc[m][n];
      float bb = bias[gn];
      if (EPI == 0) {
        #pragma unroll
        for (int r = 0; r < 4; ++r)
          outb[(size_t)(gm0 + r) * N + gn] = (__bf16)(a[r] + bb);
      } else if (EPI == 1) {
        #pragma unroll
        for (int r = 0; r < 4; ++r) {
          int dst = tokmap[gm0 + r];
          size_t idx = (size_t)dst * DIM + gn;
          outf[idx] = resid[idx] + a[r] + bb;
        }
      } else if (EPI == 2) {
        #pragma unroll
        for (int r = 0; r < 4; ++r) {
          float vv = a[r] + bb;
          outb[(size_t)(gm0 + r) * N + gn] =
              (__bf16)(0.5f * vv * (1.0f + erff(vv * 0.70710678118654752f)));
        }
      } else {
        #pragma unroll
        for (int r = 0; r < 4; ++r) {
          size_t idx = (size_t)(gm0 + r) * N + gn;
          outf[idx] = resid[idx] + a[r] + bb;
        }
      }
    }
  }
}

// ---------------- window attention: 1 wave per (window, head, mi-tile) ----------------
// Each block: 16 q-rows. S=QK^T via MFMA from global, packed-bias f32x4 adds,
// in-register softmax (16-lane shfl), P-tile (16x128) -> 4KB LDS (swizzled),
// PV via MFMA with V^T b-frags loaded straight from global vt.
__global__ __launch_bounds__(64) void attn_k(const __bf16* __restrict__ qkv,
                                             const __bf16* __restrict__ vt,
                                             const float* __restrict__ pb,
                                             __bf16* __restrict__ out) {
  __shared__ __align__(1024) char P[4096];
  const int l = threadIdx.x, lr = l & 15, lg = l >> 4;
  // XCD swizzle: all 7 mi-blocks of one (win,head) on the same XCD, near-consecutive
  const int bid = blockIdx.x;
  const int xc = bid & 7, kk = bid >> 3;
  const int wh = (kk / 7) * 8 + xc, mi = kk % 7;
  const int win = wh / NHEADS, h = wh - win * NHEADS;
  const size_t wbase = (size_t)win * 98 * QKV_DIM;
  const __bf16* qb = qkv + wbase + h * 32;
  const __bf16* kb = qb + 384;
  const bf16x8 z8 = {};
  const f32x4 fz = {};

  // issue all loads up front
  bf16x8 kf[7];
  #pragma unroll
  for (int ni = 0; ni < 7; ++ni) {
    int tok = ni * 16 + lr;
    kf[ni] = (tok < 98) ? *(const bf16x8*)(kb + (size_t)tok * QKV_DIM + lg * 8) : z8;
  }
  int qt = mi * 16 + lr;
  bf16x8 qf = (qt < 98) ? *(const bf16x8*)(qb + (size_t)qt * QKV_DIM + lg * 8) : z8;
  const f32x4* pbp = (const f32x4*)pb + (size_t)((h * 7 + mi) * 7) * 64 + l;
  f32x4 bv[7];
  #pragma unroll
  for (int ni = 0; ni < 7; ++ni) bv[ni] = pbp[ni * 64];

  f32x4 s[7];
  #pragma unroll
  for (int ni = 0; ni < 7; ++ni)
    s[ni] = __builtin_amdgcn_mfma_f32_16x16x32_bf16(qf, kf[ni], fz, 0, 0, 0);

  // zero logical pad chunks 14,15 of the P tile (swizzled like data writes)
  if (l < 32) {
    int row = l >> 1, c = 14 + (l & 1);
    *(f32x4*)(P + row * 256 + ((c ^ (row & 7)) << 4)) = fz;
  }

  // softmax: row i = mi*16 + lg*4 + r, cols j = ni*16 + lr (mask pre-baked in bv)
  #pragma unroll
  for (int r = 0; r < 4; ++r) {
    float mx = -1e30f;
    #pragma unroll
    for (int ni = 0; ni < 7; ++ni) {
      float vv = s[ni][r] + bv[ni][r];
      s[ni][r] = vv;
      mx = fmaxf(mx, vv);
    }
    #pragma unroll
    for (int m2 = 1; m2 < 16; m2 <<= 1) mx = fmaxf(mx, __shfl_xor(mx, m2, 64));
    float sum = 0.f;
    #pragma unroll
    for (int ni = 0; ni < 7; ++ni) { float p = __expf(s[ni][r] - mx); s[ni][r] = p; sum += p; }
    #pragma unroll
    for (int m2 = 1; m2 < 16; m2 <<= 1) sum += __shfl_xor(sum, m2, 64);
    float inv = 1.0f / sum;
    int il = lg * 4 + r;
    #pragma unroll
    for (int ni = 0; ni < 7; ++ni) {
      int j = ni * 16 + lr;
      *(__bf16*)(P + il * 256 + (((j >> 3) ^ (il & 7)) << 4) + ((j & 7) << 1)) =
          (__bf16)(s[ni][r] * inv);
    }
  }
  __syncthreads();

  // PV: A-frag = P rows (local row = lr), B-frag = vt rows (d), k = tok (128 padded)
  bf16x8 pa[4];
  #pragma unroll
  for (int ks = 0; ks < 4; ++ks) {
    int ck = ks * 4 + lg;
    pa[ks] = *(const bf16x8*)(P + lr * 256 + ((ck ^ (lr & 7)) << 4));
  }
  const __bf16* vrow = vt + ((size_t)wh * 32) * 128;
  __bf16* ob = out + ((size_t)win * 98 + mi * 16) * DIM + h * 32;
  #pragma unroll
  for (int nf = 0; nf < 2; ++nf) {
    int d = nf * 16 + lr;
    f32x4 o = fz;
    #pragma unroll
    for (int ks = 0; ks < 4; ++ks) {
      bf16x8 vb = *(const bf16x8*)(vrow + (size_t)d * 128 + ks * 32 + lg * 8);
      o = __builtin_amdgcn_mfma_f32_16x16x32_bf16(pa[ks], vb, o, 0, 0, 0);
    }
    #pragma unroll
    for (int r = 0; r < 4; ++r) {
      int il = lg * 4 + r;
      if (mi * 16 + il < 98) ob[(size_t)il * DIM + nf * 16 + lr] = (__bf16)o[r];
    }
  }
}

// ---------------- launch ----------------
extern "C" void kernel_launch(void* const* d_in, const int* in_sizes, int n_in,
                              void* d_out, int out_size, void* d_ws, size_t ws_size,
                              hipStream_t stream) {
  const float* x      = (const float*)d_in[0];
  const float* n1g    = (const float*)d_in[1];
  const float* n1b    = (const float*)d_in[2];
  const float* qkv_w  = (const float*)d_in[3];
  const float* qkv_b  = (const float*)d_in[4];
  const float* proj_w = (const float*)d_in[5];
  const float* proj_b = (const float*)d_in[6];
  const float* btab   = (const float*)d_in[7];
  const float* n2g    = (const float*)d_in[8];
  const float* n2b    = (const float*)d_in[9];
  const float* fc1_w  = (const float*)d_in[10];
  const float* fc1_b  = (const float*)d_in[11];
  const float* fc2_w  = (const float*)d_in[12];
  const float* fc2_b  = (const float*)d_in[13];
  const int*   relidx = (const int*)d_in[14];
  float* outp = (float*)d_out;
  (void)in_sizes; (void)n_in; (void)out_size; (void)ws_size;

  char* ws = (char*)d_ws;
  size_t off = 0;
  auto alloc = [&](size_t bytes) {
    char* p = ws + off;
    off = (off + bytes + 255) & ~(size_t)255;
    return p;
  };
  int*    tokmap = (int*)alloc((size_t)NTOK * 4);
  float*  biasex = (float*)alloc((size_t)NHEADS * 49 * 256 * 4);
  __bf16* wqkvT  = (__bf16*)alloc((size_t)QKV_DIM * DIM * 2);
  __bf16* wprojT = (__bf16*)alloc((size_t)DIM * DIM * 2);
  __bf16* wfc1T  = (__bf16*)alloc((size_t)HID * DIM * 2);
  __bf16* wfc2T  = (__bf16*)alloc((size_t)DIM * HID * 2);
  float*  qkvbS  = (float*)alloc((size_t)QKV_DIM * 4);
  __bf16* tokens = (__bf16*)alloc((size_t)NTOK * DIM * 2);   // LN1 out / attn out / LN2 out
  __bf16* qkvbuf = (__bf16*)alloc((size_t)NTOK * HID * 2);   // qkv (1152) then h1 (1536)
  __bf16* attnout = tokens;
  __bf16* h1 = qkvbuf;
  // vt (50.3MB) lives in d_out (77MB fp32) — proj overwrites d_out afterwards
  __bf16* vt = (__bf16*)d_out;

  const float scale = 0.17677669529663687f;  // 1/sqrt(32)

  build_tokmap_k<<<NTOK / 256, 256, 0, stream>>>(tokmap);
  expand_biasp_k<<<(NHEADS * 49 * 256) / 256, 256, 0, stream>>>(btab, relidx, biasex);
  transpose_w_k<<<(DIM * QKV_DIM) / 256, 256, 0, stream>>>(qkv_w, wqkvT, DIM, QKV_DIM, DIM, scale);
  transpose_w_k<<<(DIM * DIM) / 256, 256, 0, stream>>>(proj_w, wprojT, DIM, DIM, 0, 1.0f);
  transpose_w_k<<<(DIM * HID) / 256, 256, 0, stream>>>(fc1_w, wfc1T, DIM, HID, 0, 1.0f);
  transpose_w_k<<<(HID * DIM) / 256, 256, 0, stream>>>(fc2_w, wfc2T, HID, DIM, 0, 1.0f);
  scale_bias_k<<<(QKV_DIM + 255) / 256, 256, 0, stream>>>(qkv_b, qkvbS, QKV_DIM, DIM, scale);

  ln_k<<<NTOK / 4, 256, 0, stream>>>(x, n1g, n1b, tokens, tokmap);
  gemm_k<0><<<(NTOK / 128) * (QKV_DIM / 128), 256, 0, stream>>>(
      tokens, wqkvT, qkvbS, NTOK, QKV_DIM, DIM, qkvbuf, nullptr, nullptr, nullptr);
  vtrans_k<<<NWIN, 384, 0, stream>>>(qkvbuf, vt);
  attn_k<<<NWIN * NHEADS * 7, 64, 0, stream>>>(qkvbuf, vt, biasex, attnout);
  gemm_k<1><<<(NTOK / 128) * (DIM / 128), 256, 0, stream>>>(
      attnout, wprojT, proj_b, NTOK, DIM, DIM, nullptr, outp, x, tokmap);
  ln_k<<<NTOK / 4, 256, 0, stream>>>(outp, n2g, n2b, tokens, nullptr);
  gemm_k<2><<<(NTOK / 128) * (HID / 128), 256, 0, stream>>>(
      tokens, wfc1T, fc1_b, NTOK, HID, DIM, h1, nullptr, nullptr, nullptr);
  gemm_k<3><<<(NTOK / 128) * (DIM / 128), 256, 0, stream>>>(
      h1, wfc2T, fc2_b, NTOK, DIM, HID, nullptr, outp, outp, nullptr);
}

// Round 3
// 519.153 us; speedup vs baseline: 1.5464x; 1.0072x over previous
//
#include <hip/hip_runtime.h>
#include <cstdint>
#include <cstddef>

// SwinBlock3D: LN1 -> roll(-1,-3,-3) -> window(2,7,7) attn (12 heads, rel-bias)
// -> proj + resid -> LN2 -> MLP(384->1536 gelu ->384) + resid.
// bf16 MFMA for all matmuls, fp32 LN/softmax/residuals.

typedef __bf16 bf16x8 __attribute__((ext_vector_type(8)));
typedef float f32x4 __attribute__((ext_vector_type(4)));

#define DIM 384
#define QKV_DIM 1152
#define HID 1536
#define NHEADS 12
#define NTOK 50176
#define NWIN 512

// async global->LDS, 16B per lane; LDS dest = wave-uniform base + lane*16
__device__ __forceinline__ void gload16(const void* g, void* s) {
  __builtin_amdgcn_global_load_lds(
      (const __attribute__((address_space(1))) void*)g,
      (__attribute__((address_space(3))) void*)s, 16, 0, 0);
}

// ---------------- prep kernels ----------------
__global__ __launch_bounds__(256) void build_tokmap_k(int* __restrict__ map) {
  int t = blockIdx.x * 256 + threadIdx.x;
  if (t >= NTOK) return;
  int win = t / 98, n = t - win * 98;
  int b = win >> 8, tw = (win >> 6) & 3, hw = (win >> 3) & 7, ww = win & 7;
  int dt = n / 49; int rem = n - dt * 49; int dh = rem / 7, dw = rem - dh * 7;
  int t0 = (tw * 2 + dt + 1) & 7;                 // roll by shift (1,3,3)
  int h0 = hw * 7 + dh + 3; if (h0 >= 56) h0 -= 56;
  int w0 = ww * 7 + dw + 3; if (w0 >= 56) w0 -= 56;
  map[t] = ((b * 8 + t0) * 56 + h0) * 56 + w0;    // spatial row for window-token t
}

// packed bias in MFMA-fragment order: pb[h][mi][ni][lane][r], j>=98 mask pre-baked
__global__ __launch_bounds__(256) void expand_biasp_k(const float* __restrict__ table,
                                                      const int* __restrict__ rel,
                                                      float* __restrict__ out) {
  int e = blockIdx.x * 256 + threadIdx.x;
  if (e >= NHEADS * 49 * 256) return;
  int r = e & 3, l = (e >> 2) & 63;
  int rest = e >> 8;
  int ni = rest % 7, mi = (rest / 7) % 7, h = rest / 49;
  int i = mi * 16 + (l >> 4) * 4 + r;
  int j = ni * 16 + (l & 15);
  float v;
  if (j >= 98) v = -1e30f;          // pad-column mask baked in
  else if (i >= 98) v = 0.f;
  else v = table[rel[i * 98 + j] * NHEADS + h];
  out[e] = v;
}

__global__ __launch_bounds__(256) void transpose_w_k(const float* __restrict__ W,
                                                     __bf16* __restrict__ WT,
                                                     int K, int N, int scaleCols, float scale) {
  int e = blockIdx.x * 256 + threadIdx.x;
  if (e >= K * N) return;
  int n = e / K, k = e - n * K;
  float v = W[(size_t)k * N + n];
  if (n < scaleCols) v *= scale;                  // fold q-scale into W_q
  WT[e] = (__bf16)v;                              // WT[n][k]
}

__global__ __launch_bounds__(256) void scale_bias_k(const float* __restrict__ b,
                                                    float* __restrict__ out,
                                                    int n, int scaleCols, float scale) {
  int e = blockIdx.x * 256 + threadIdx.x;
  if (e >= n) return;
  out[e] = b[e] * (e < scaleCols ? scale : 1.0f);
}

// V^T: vt[(win*12+h)*32 + d][tok 0..127] bf16, zeros past tok 97
__global__ __launch_bounds__(384) void vtrans_k(const __bf16* __restrict__ qkv,
                                                __bf16* __restrict__ vt) {
  int win = blockIdx.x, t = threadIdx.x;          // t = h*32+d
  const __bf16* base = qkv + (size_t)win * 98 * QKV_DIM + 768 + t;
  __bf16* orow = vt + ((size_t)win * 384 + t) * 128;
  #pragma unroll
  for (int c = 0; c < 16; ++c) {
    bf16x8 pk;
    #pragma unroll
    for (int e2 = 0; e2 < 8; ++e2) {
      int tok = c * 8 + e2;
      pk[e2] = (tok < 98) ? base[(size_t)tok * QKV_DIM] : (__bf16)0.f;
    }
    *(bf16x8*)(orow + c * 8) = pk;
  }
}

// ---------------- layernorm (1 wave per token row of 384) ----------------
__global__ __launch_bounds__(256) void ln_k(const float* __restrict__ x,
                                            const float* __restrict__ g,
                                            const float* __restrict__ bta,
                                            __bf16* __restrict__ out,
                                            const int* __restrict__ map) {
  int w = threadIdx.x >> 6, l = threadIdx.x & 63;
  int tok = blockIdx.x * 4 + w;
  int src = map ? map[tok] : tok;
  const float* row = x + (size_t)src * DIM;
  float v[6]; float s = 0.f;
  #pragma unroll
  for (int j = 0; j < 6; ++j) { v[j] = row[l + 64 * j]; s += v[j]; }
  #pragma unroll
  for (int m = 1; m < 64; m <<= 1) s += __shfl_xor(s, m, 64);
  float mu = s * (1.f / DIM);
  float var = 0.f;
  #pragma unroll
  for (int j = 0; j < 6; ++j) { float d = v[j] - mu; var += d * d; }
  #pragma unroll
  for (int m = 1; m < 64; m <<= 1) var += __shfl_xor(var, m, 64);
  float rs = rsqrtf(var * (1.f / DIM) + 1e-5f);
  __bf16* orow = out + (size_t)tok * DIM;
  #pragma unroll
  for (int j = 0; j < 6; ++j) {
    int c = l + 64 * j;
    orow[c] = (__bf16)((v[j] - mu) * rs * g[c] + bta[c]);
  }
}

// ---------------- 128x128 bf16 MFMA GEMM, BK=64, 4 waves, global_load_lds ----
// A[M][K] bf16 row-major, BT[N][K] bf16 row-major. C = A @ BT^T.
// Staging: global_load_lds width=16, XOR swizzle carried by per-lane GLOBAL
// source chunk ((l&7)^(l>>3)); LDS dest linear; frag reads use chunk^(row&7).
// EPI: 0 = +bias -> bf16   1 = +bias, scatter via tokmap, +resid -> fp32
//      2 = +bias, fast-gelu -> bf16   3 = +bias, +resid -> fp32 (linear)
template <int EPI>
__global__ __launch_bounds__(256) void gemm_k(const __bf16* __restrict__ A,
                                              const __bf16* __restrict__ BT,
                                              const float* __restrict__ bias,
                                              int M, int N, int K,
                                              __bf16* __restrict__ outb,
                                              float* __restrict__ outf,
                                              const float* __restrict__ resid,
                                              const int* __restrict__ tokmap) {
  __shared__ __align__(1024) char sA[16384];
  __shared__ __align__(1024) char sB[16384];
  const int tid = threadIdx.x;
  const int l = tid & 63, w = tid >> 6;
  const int lr = l & 15, lg = l >> 4;
  const int ntile = N >> 7;
  // XCD chunking: contiguous run of bids per XCD (all grids divisible by 8)
  const int nwg8 = gridDim.x >> 3;
  const int bid = (blockIdx.x & 7) * nwg8 + (blockIdx.x >> 3);
  const int bm = bid / ntile, bn = bid - bm * ntile;
  const int m0 = bm << 7, n0 = bn << 7;
  const int wr = w >> 1, wc = w & 1;
  // staging: lane covers row (l>>3) of an 8-row group; source chunk pre-swizzled
  const int srow = l >> 3;
  const int sch = (l & 7) ^ srow;
  const __bf16* pa = A + (size_t)(m0 + w * 32 + srow) * K + sch * 8;
  const __bf16* pb = BT + (size_t)(n0 + w * 32 + srow) * K + sch * 8;
  char* dA = sA + w * 32 * 128;
  char* dB = sB + w * 32 * 128;

  f32x4 acc[4][4] = {};
  const int nk = K >> 6;
  for (int kt = 0; kt < nk; ++kt) {
    const int koff = kt << 6;
    __syncthreads();
    #pragma unroll
    for (int i = 0; i < 4; ++i) {
      gload16(pa + (size_t)(i * 8) * K + koff, dA + i * 1024);
      gload16(pb + (size_t)(i * 8) * K + koff, dB + i * 1024);
    }
    __syncthreads();   // compiler drains vmcnt(0) before barrier
    #pragma unroll
    for (int kk = 0; kk < 2; ++kk) {
      bf16x8 af[4], bfv[4];
      const int ck = (kk << 2) + lg;
      #pragma unroll
      for (int m = 0; m < 4; ++m) {
        int r = (wr << 6) + (m << 4) + lr;
        af[m] = *(const bf16x8*)(sA + (r << 7) + ((ck ^ (r & 7)) << 4));
      }
      #pragma unroll
      for (int n = 0; n < 4; ++n) {
        int r = (wc << 6) + (n << 4) + lr;
        bfv[n] = *(const bf16x8*)(sB + (r << 7) + ((ck ^ (r & 7)) << 4));
      }
      #pragma unroll
      for (int m = 0; m < 4; ++m)
        #pragma unroll
        for (int n = 0; n < 4; ++n)
          acc[m][n] = __builtin_amdgcn_mfma_f32_16x16x32_bf16(af[m], bfv[n], acc[m][n], 0, 0, 0);
    }
  }
  // epilogue: C row = (lane>>4)*4 + reg, col = lane&15
  #pragma unroll
  for (int m = 0; m < 4; ++m) {
    int gm0 = m0 + (wr << 6) + (m << 4) + (lg << 2);
    #pragma unroll
    for (int n = 0; n < 4; ++n) {
      int gn = n0 + (wc << 6) + (n << 4) + lr;
      f32x4 a = acc[m][n];
      float bb = bias[gn];
      if (EPI == 0) {
        #pragma unroll
        for (int r = 0; r < 4; ++r)
          outb[(size_t)(gm0 + r) * N + gn] = (__bf16)(a[r] + bb);
      } else if (EPI == 1) {
        #pragma unroll
        for (int r = 0; r < 4; ++r) {
          int dst = tokmap[gm0 + r];
          size_t idx = (size_t)dst * DIM + gn;
          outf[idx] = resid[idx] + a[r] + bb;
        }
      } else if (EPI == 2) {
        #pragma unroll
        for (int r = 0; r < 4; ++r) {
          float vv = a[r] + bb;
          // gelu via sigmoid-form tanh approx (max err ~1e-3 << bf16 thresh)
          float y = vv * (1.0f + 0.044715f * vv * vv);
          outb[(size_t)(gm0 + r) * N + gn] =
              (__bf16)(vv / (1.0f + __expf(-1.5957691216057308f * y)));
        }
      } else {
        #pragma unroll
        for (int r = 0; r < 4; ++r) {
          size_t idx = (size_t)(gm0 + r) * N + gn;
          outf[idx] = resid[idx] + a[r] + bb;
        }
      }
    }
  }
}

// ---------------- window attention: 1 wave per (window, head, mi-tile) ----------------
__global__ __launch_bounds__(64) void attn_k(const __bf16* __restrict__ qkv,
                                             const __bf16* __restrict__ vt,
                                             const float* __restrict__ pb,
                                             __bf16* __restrict__ out) {
  __shared__ __align__(1024) char P[4096];
  const int l = threadIdx.x, lr = l & 15, lg = l >> 4;
  const int bid = blockIdx.x;
  const int xc = bid & 7, kk = bid >> 3;
  const int wh = (kk / 7) * 8 + xc, mi = kk % 7;
  const int win = wh / NHEADS, h = wh - win * NHEADS;
  const size_t wbase = (size_t)win * 98 * QKV_DIM;
  const __bf16* qb = qkv + wbase + h * 32;
  const __bf16* kb = qb + 384;
  const bf16x8 z8 = {};
  const f32x4 fz = {};

  bf16x8 kf[7];
  #pragma unroll
  for (int ni = 0; ni < 7; ++ni) {
    int tok = ni * 16 + lr;
    kf[ni] = (tok < 98) ? *(const bf16x8*)(kb + (size_t)tok * QKV_DIM + lg * 8) : z8;
  }
  int qt = mi * 16 + lr;
  bf16x8 qf = (qt < 98) ? *(const bf16x8*)(qb + (size_t)qt * QKV_DIM + lg * 8) : z8;
  const f32x4* pbp = (const f32x4*)pb + (size_t)((h * 7 + mi) * 7) * 64 + l;
  f32x4 bv[7];
  #pragma unroll
  for (int ni = 0; ni < 7; ++ni) bv[ni] = pbp[ni * 64];

  f32x4 s[7];
  #pragma unroll
  for (int ni = 0; ni < 7; ++ni)
    s[ni] = __builtin_amdgcn_mfma_f32_16x16x32_bf16(qf, kf[ni], fz, 0, 0, 0);

  if (l < 32) {
    int row = l >> 1, c = 14 + (l & 1);
    *(f32x4*)(P + row * 256 + ((c ^ (row & 7)) << 4)) = fz;
  }

  #pragma unroll
  for (int r = 0; r < 4; ++r) {
    float mx = -1e30f;
    #pragma unroll
    for (int ni = 0; ni < 7; ++ni) {
      float vv = s[ni][r] + bv[ni][r];
      s[ni][r] = vv;
      mx = fmaxf(mx, vv);
    }
    #pragma unroll
    for (int m2 = 1; m2 < 16; m2 <<= 1) mx = fmaxf(mx, __shfl_xor(mx, m2, 64));
    float sum = 0.f;
    #pragma unroll
    for (int ni = 0; ni < 7; ++ni) { float p = __expf(s[ni][r] - mx); s[ni][r] = p; sum += p; }
    #pragma unroll
    for (int m2 = 1; m2 < 16; m2 <<= 1) sum += __shfl_xor(sum, m2, 64);
    float inv = 1.0f / sum;
    int il = lg * 4 + r;
    #pragma unroll
    for (int ni = 0; ni < 7; ++ni) {
      int j = ni * 16 + lr;
      *(__bf16*)(P + il * 256 + (((j >> 3) ^ (il & 7)) << 4) + ((j & 7) << 1)) =
          (__bf16)(s[ni][r] * inv);
    }
  }
  __syncthreads();

  bf16x8 pa[4];
  #pragma unroll
  for (int ks = 0; ks < 4; ++ks) {
    int ck = ks * 4 + lg;
    pa[ks] = *(const bf16x8*)(P + lr * 256 + ((ck ^ (lr & 7)) << 4));
  }
  const __bf16* vrow = vt + ((size_t)wh * 32) * 128;
  __bf16* ob = out + ((size_t)win * 98 + mi * 16) * DIM + h * 32;
  #pragma unroll
  for (int nf = 0; nf < 2; ++nf) {
    int d = nf * 16 + lr;
    f32x4 o = fz;
    #pragma unroll
    for (int ks = 0; ks < 4; ++ks) {
      bf16x8 vb = *(const bf16x8*)(vrow + (size_t)d * 128 + ks * 32 + lg * 8);
      o = __builtin_amdgcn_mfma_f32_16x16x32_bf16(pa[ks], vb, o, 0, 0, 0);
    }
    #pragma unroll
    for (int r = 0; r < 4; ++r) {
      int il = lg * 4 + r;
      if (mi * 16 + il < 98) ob[(size_t)il * DIM + nf * 16 + lr] = (__bf16)o[r];
    }
  }
}

// ---------------- launch ----------------
extern "C" void kernel_launch(void* const* d_in, const int* in_sizes, int n_in,
                              void* d_out, int out_size, void* d_ws, size_t ws_size,
                              hipStream_t stream) {
  const float* x      = (const float*)d_in[0];
  const float* n1g    = (const float*)d_in[1];
  const float* n1b    = (const float*)d_in[2];
  const float* qkv_w  = (const float*)d_in[3];
  const float* qkv_b  = (const float*)d_in[4];
  const float* proj_w = (const float*)d_in[5];
  const float* proj_b = (const float*)d_in[6];
  const float* btab   = (const float*)d_in[7];
  const float* n2g    = (const float*)d_in[8];
  const float* n2b    = (const float*)d_in[9];
  const float* fc1_w  = (const float*)d_in[10];
  const float* fc1_b  = (const float*)d_in[11];
  const float* fc2_w  = (const float*)d_in[12];
  const float* fc2_b  = (const float*)d_in[13];
  const int*   relidx = (const int*)d_in[14];
  float* outp = (float*)d_out;
  (void)in_sizes; (void)n_in; (void)out_size; (void)ws_size;

  char* ws = (char*)d_ws;
  size_t off = 0;
  auto alloc = [&](size_t bytes) {
    char* p = ws + off;
    off = (off + bytes + 255) & ~(size_t)255;
    return p;
  };
  int*    tokmap = (int*)alloc((size_t)NTOK * 4);
  float*  biasex = (float*)alloc((size_t)NHEADS * 49 * 256 * 4);
  __bf16* wqkvT  = (__bf16*)alloc((size_t)QKV_DIM * DIM * 2);
  __bf16* wprojT = (__bf16*)alloc((size_t)DIM * DIM * 2);
  __bf16* wfc1T  = (__bf16*)alloc((size_t)HID * DIM * 2);
  __bf16* wfc2T  = (__bf16*)alloc((size_t)DIM * HID * 2);
  float*  qkvbS  = (float*)alloc((size_t)QKV_DIM * 4);
  __bf16* tokens = (__bf16*)alloc((size_t)NTOK * DIM * 2);   // LN1 out / attn out / LN2 out
  __bf16* qkvbuf = (__bf16*)alloc((size_t)NTOK * HID * 2);   // qkv (1152) then h1 (1536)
  __bf16* attnout = tokens;
  __bf16* h1 = qkvbuf;
  // vt (50.3MB) lives in d_out (77MB fp32) — proj overwrites d_out afterwards
  __bf16* vt = (__bf16*)d_out;

  const float scale = 0.17677669529663687f;  // 1/sqrt(32)

  build_tokmap_k<<<NTOK / 256, 256, 0, stream>>>(tokmap);
  expand_biasp_k<<<(NHEADS * 49 * 256) / 256, 256, 0, stream>>>(btab, relidx, biasex);
  transpose_w_k<<<(DIM * QKV_DIM) / 256, 256, 0, stream>>>(qkv_w, wqkvT, DIM, QKV_DIM, DIM, scale);
  transpose_w_k<<<(DIM * DIM) / 256, 256, 0, stream>>>(proj_w, wprojT, DIM, DIM, 0, 1.0f);
  transpose_w_k<<<(DIM * HID) / 256, 256, 0, stream>>>(fc1_w, wfc1T, DIM, HID, 0, 1.0f);
  transpose_w_k<<<(HID * DIM) / 256, 256, 0, stream>>>(fc2_w, wfc2T, HID, DIM, 0, 1.0f);
  scale_bias_k<<<(QKV_DIM + 255) / 256, 256, 0, stream>>>(qkv_b, qkvbS, QKV_DIM, DIM, scale);

  ln_k<<<NTOK / 4, 256, 0, stream>>>(x, n1g, n1b, tokens, tokmap);
  gemm_k<0><<<(NTOK / 128) * (QKV_DIM / 128), 256, 0, stream>>>(
      tokens, wqkvT, qkvbS, NTOK, QKV_DIM, DIM, qkvbuf, nullptr, nullptr, nullptr);
  vtrans_k<<<NWIN, 384, 0, stream>>>(qkvbuf, vt);
  attn_k<<<NWIN * NHEADS * 7, 64, 0, stream>>>(qkvbuf, vt, biasex, attnout);
  gemm_k<1><<<(NTOK / 128) * (DIM / 128), 256, 0, stream>>>(
      attnout, wprojT, proj_b, NTOK, DIM, DIM, nullptr, outp, x, tokmap);
  ln_k<<<NTOK / 4, 256, 0, stream>>>(outp, n2g, n2b, tokens, nullptr);
  gemm_k<2><<<(NTOK / 128) * (HID / 128), 256, 0, stream>>>(
      tokens, wfc1T, fc1_b, NTOK, HID, DIM, h1, nullptr, nullptr, nullptr);
  gemm_k<3><<<(NTOK / 128) * (DIM / 128), 256, 0, stream>>>(
      h1, wfc2T, fc2_b, NTOK, DIM, HID, nullptr, outp, outp, nullptr);
}

// Round 4
// 483.121 us; speedup vs baseline: 1.6618x; 1.0746x over previous
//
#include <hip/hip_runtime.h>
#include <cstdint>
#include <cstddef>

// SwinBlock3D: LN1 -> roll(-1,-3,-3) -> window(2,7,7) attn (12 heads, rel-bias)
// -> proj + resid -> LN2 -> MLP(384->1536 gelu ->384) + resid.
// bf16 MFMA for all matmuls, fp32 LN/softmax/residuals.

typedef __bf16 bf16x8 __attribute__((ext_vector_type(8)));
typedef __bf16 bf16x4 __attribute__((ext_vector_type(4)));
typedef float f32x4 __attribute__((ext_vector_type(4)));

#define DIM 384
#define QKV_DIM 1152
#define HID 1536
#define NHEADS 12
#define NTOK 50176
#define NWIN 512

// async global->LDS, 16B per lane; LDS dest = wave-uniform base + lane*16
__device__ __forceinline__ void gload16(const void* g, void* s) {
  __builtin_amdgcn_global_load_lds(
      (const __attribute__((address_space(1))) void*)g,
      (__attribute__((address_space(3))) void*)s, 16, 0, 0);
}

// ---------------- prep kernels ----------------
__global__ __launch_bounds__(256) void build_tokmap_k(int* __restrict__ map) {
  int t = blockIdx.x * 256 + threadIdx.x;
  if (t >= NTOK) return;
  int win = t / 98, n = t - win * 98;
  int b = win >> 8, tw = (win >> 6) & 3, hw = (win >> 3) & 7, ww = win & 7;
  int dt = n / 49; int rem = n - dt * 49; int dh = rem / 7, dw = rem - dh * 7;
  int t0 = (tw * 2 + dt + 1) & 7;                 // roll by shift (1,3,3)
  int h0 = hw * 7 + dh + 3; if (h0 >= 56) h0 -= 56;
  int w0 = ww * 7 + dw + 3; if (w0 >= 56) w0 -= 56;
  map[t] = ((b * 8 + t0) * 56 + h0) * 56 + w0;    // spatial row for window-token t
}

// packed bias in MFMA-fragment order: pb[h][mi][ni][lane][r], j>=98 mask pre-baked
__global__ __launch_bounds__(256) void expand_biasp_k(const float* __restrict__ table,
                                                      const int* __restrict__ rel,
                                                      float* __restrict__ out) {
  int e = blockIdx.x * 256 + threadIdx.x;
  if (e >= NHEADS * 49 * 256) return;
  int r = e & 3, l = (e >> 2) & 63;
  int rest = e >> 8;
  int ni = rest % 7, mi = (rest / 7) % 7, h = rest / 49;
  int i = mi * 16 + (l >> 4) * 4 + r;
  int j = ni * 16 + (l & 15);
  float v;
  if (j >= 98) v = -1e30f;          // pad-column mask baked in
  else if (i >= 98) v = 0.f;
  else v = table[rel[i * 98 + j] * NHEADS + h];
  out[e] = v;
}

__global__ __launch_bounds__(256) void transpose_w_k(const float* __restrict__ W,
                                                     __bf16* __restrict__ WT,
                                                     int K, int N, int scaleCols, float scale) {
  int e = blockIdx.x * 256 + threadIdx.x;
  if (e >= K * N) return;
  int n = e / K, k = e - n * K;
  float v = W[(size_t)k * N + n];
  if (n < scaleCols) v *= scale;                  // fold q-scale into W_q
  WT[e] = (__bf16)v;                              // WT[n][k]
}

__global__ __launch_bounds__(256) void scale_bias_k(const float* __restrict__ b,
                                                    float* __restrict__ out,
                                                    int n, int scaleCols, float scale) {
  int e = blockIdx.x * 256 + threadIdx.x;
  if (e >= n) return;
  out[e] = b[e] * (e < scaleCols ? scale : 1.0f);
}

// V^T: vt[(win*12+h)*32 + d][tok 0..127] bf16, zeros past tok 97
__global__ __launch_bounds__(384) void vtrans_k(const __bf16* __restrict__ qkv,
                                                __bf16* __restrict__ vt) {
  int win = blockIdx.x, t = threadIdx.x;          // t = h*32+d
  const __bf16* base = qkv + (size_t)win * 98 * QKV_DIM + 768 + t;
  __bf16* orow = vt + ((size_t)win * 384 + t) * 128;
  #pragma unroll
  for (int c = 0; c < 16; ++c) {
    bf16x8 pk;
    #pragma unroll
    for (int e2 = 0; e2 < 8; ++e2) {
      int tok = c * 8 + e2;
      pk[e2] = (tok < 98) ? base[(size_t)tok * QKV_DIM] : (__bf16)0.f;
    }
    *(bf16x8*)(orow + c * 8) = pk;
  }
}

// ---------------- layernorm (1 wave per token row of 384) ----------------
__global__ __launch_bounds__(256) void ln_k(const float* __restrict__ x,
                                            const float* __restrict__ g,
                                            const float* __restrict__ bta,
                                            __bf16* __restrict__ out,
                                            const int* __restrict__ map) {
  int w = threadIdx.x >> 6, l = threadIdx.x & 63;
  int tok = blockIdx.x * 4 + w;
  int src = map ? map[tok] : tok;
  const float* row = x + (size_t)src * DIM;
  float v[6]; float s = 0.f;
  #pragma unroll
  for (int j = 0; j < 6; ++j) { v[j] = row[l + 64 * j]; s += v[j]; }
  #pragma unroll
  for (int m = 1; m < 64; m <<= 1) s += __shfl_xor(s, m, 64);
  float mu = s * (1.f / DIM);
  float var = 0.f;
  #pragma unroll
  for (int j = 0; j < 6; ++j) { float d = v[j] - mu; var += d * d; }
  #pragma unroll
  for (int m = 1; m < 64; m <<= 1) var += __shfl_xor(var, m, 64);
  float rs = rsqrtf(var * (1.f / DIM) + 1e-5f);
  __bf16* orow = out + (size_t)tok * DIM;
  #pragma unroll
  for (int j = 0; j < 6; ++j) {
    int c = l + 64 * j;
    orow[c] = (__bf16)((v[j] - mu) * rs * g[c] + bta[c]);
  }
}

// ---------------- 128x128 bf16 MFMA GEMM, BK=64, 4 waves ----------------
// Double-buffered global_load_lds pipeline with counted vmcnt (T3/T4-lite):
//   issue tile k+1 -> vmcnt(8) waits tile k only -> barrier -> compute k -> barrier
// MFMA operands SWAPPED (bfv, af) so acc holds C^T fragments: per lane each
// acc[m][n] = 4 CONSECUTIVE C-columns of one row -> vectorized epilogue stores.
// EPI: 0 = +bias -> bf16   1 = +bias, scatter via tokmap, +resid -> fp32
//      2 = +bias, fast-gelu -> bf16   3 = +bias, +resid -> fp32 (linear)
template <int EPI>
__global__ __launch_bounds__(256) void gemm_k(const __bf16* __restrict__ A,
                                              const __bf16* __restrict__ BT,
                                              const float* __restrict__ bias,
                                              int M, int N, int K,
                                              __bf16* __restrict__ outb,
                                              float* __restrict__ outf,
                                              const float* __restrict__ resid,
                                              const int* __restrict__ tokmap) {
  __shared__ __align__(1024) char lds[65536];     // 2 buffers x (A 16K | B 16K)
  const int tid = threadIdx.x;
  const int l = tid & 63, w = tid >> 6;
  const int lr = l & 15, lg = l >> 4;
  const int ntile = N >> 7;
  // XCD chunking: contiguous run of bids per XCD (all grids divisible by 8)
  const int nwg8 = gridDim.x >> 3;
  const int bid = (blockIdx.x & 7) * nwg8 + (blockIdx.x >> 3);
  const int bm = bid / ntile, bn = bid - bm * ntile;
  const int m0 = bm << 7, n0 = bn << 7;
  const int wr = w >> 1, wc = w & 1;
  // staging: lane covers row (l>>3) of an 8-row group; source chunk pre-swizzled
  const int srow = l >> 3;
  const int sch = (l & 7) ^ srow;
  const __bf16* pa = A + (size_t)(m0 + w * 32 + srow) * K + sch * 8;
  const __bf16* pb = BT + (size_t)(n0 + w * 32 + srow) * K + sch * 8;
  const int doff = w * 4096;                      // wave's 32-row staging region
  const int nk = K >> 6;

  // prologue: tile 0 -> buffer 0
  #pragma unroll
  for (int i = 0; i < 4; ++i) {
    gload16(pa + (size_t)(i * 8) * K, lds + doff + i * 1024);
    gload16(pb + (size_t)(i * 8) * K, lds + 16384 + doff + i * 1024);
  }

  f32x4 acc[4][4] = {};
  for (int kt = 0; kt < nk; ++kt) {
    char* cur = lds + ((kt & 1) << 15);
    if (kt + 1 < nk) {
      char* nxt = lds + (((kt + 1) & 1) << 15);
      const size_t koff = (size_t)(kt + 1) << 6;
      #pragma unroll
      for (int i = 0; i < 4; ++i) {
        gload16(pa + (size_t)(i * 8) * K + koff, nxt + doff + i * 1024);
        gload16(pb + (size_t)(i * 8) * K + koff, nxt + 16384 + doff + i * 1024);
      }
      asm volatile("s_waitcnt vmcnt(8)" ::: "memory");   // tile kt landed; 8 in flight
    } else {
      asm volatile("s_waitcnt vmcnt(0)" ::: "memory");
    }
    asm volatile("s_barrier" ::: "memory");              // all waves' tile-kt DMA done
    #pragma unroll
    for (int kk = 0; kk < 2; ++kk) {
      bf16x8 af[4], bfv[4];
      const int ck = (kk << 2) + lg;
      #pragma unroll
      for (int m = 0; m < 4; ++m) {
        int r = (wr << 6) + (m << 4) + lr;
        af[m] = *(const bf16x8*)(cur + (r << 7) + ((ck ^ (r & 7)) << 4));
      }
      #pragma unroll
      for (int n = 0; n < 4; ++n) {
        int r = (wc << 6) + (n << 4) + lr;
        bfv[n] = *(const bf16x8*)(cur + 16384 + (r << 7) + ((ck ^ (r & 7)) << 4));
      }
      #pragma unroll
      for (int m = 0; m < 4; ++m)
        #pragma unroll
        for (int n = 0; n < 4; ++n)   // swapped operands -> C^T fragment layout
          acc[m][n] = __builtin_amdgcn_mfma_f32_16x16x32_bf16(bfv[n], af[m], acc[m][n], 0, 0, 0);
    }
    asm volatile("s_barrier" ::: "memory");  // reads of cur done before it's re-staged
  }

  // epilogue (C^T frags): row = m0+wr*64+m*16+lr, cols = n0+wc*64+n*16+lg*4 .. +3
  #pragma unroll
  for (int m = 0; m < 4; ++m) {
    const int grow = m0 + (wr << 6) + (m << 4) + lr;
    #pragma unroll
    for (int n = 0; n < 4; ++n) {
      const int gcol = n0 + (wc << 6) + (n << 4) + (lg << 2);
      f32x4 a = acc[m][n] + *(const f32x4*)(bias + gcol);
      if (EPI == 0) {
        bf16x4 c;
        #pragma unroll
        for (int r = 0; r < 4; ++r) c[r] = (__bf16)a[r];
        *(bf16x4*)(outb + (size_t)grow * N + gcol) = c;
      } else if (EPI == 1) {
        int dst = tokmap[grow];
        f32x4 rv = *(const f32x4*)(resid + (size_t)dst * DIM + gcol);
        *(f32x4*)(outf + (size_t)dst * DIM + gcol) = rv + a;
      } else if (EPI == 2) {
        bf16x4 c;
        #pragma unroll
        for (int r = 0; r < 4; ++r) {
          float vv = a[r];
          float y = vv * (1.0f + 0.044715f * vv * vv);
          c[r] = (__bf16)(vv / (1.0f + __expf(-1.5957691216057308f * y)));
        }
        *(bf16x4*)(outb + (size_t)grow * N + gcol) = c;
      } else {
        f32x4 rv = *(const f32x4*)(resid + (size_t)grow * N + gcol);
        *(f32x4*)(outf + (size_t)grow * N + gcol) = rv + a;
      }
    }
  }
}

// ---------------- window attention: 1 wave per (window, head, mi-tile) ----------------
__global__ __launch_bounds__(64) void attn_k(const __bf16* __restrict__ qkv,
                                             const __bf16* __restrict__ vt,
                                             const float* __restrict__ pb,
                                             __bf16* __restrict__ out) {
  __shared__ __align__(1024) char P[4096];
  const int l = threadIdx.x, lr = l & 15, lg = l >> 4;
  const int bid = blockIdx.x;
  const int xc = bid & 7, kk = bid >> 3;
  const int wh = (kk / 7) * 8 + xc, mi = kk % 7;
  const int win = wh / NHEADS, h = wh - win * NHEADS;
  const size_t wbase = (size_t)win * 98 * QKV_DIM;
  const __bf16* qb = qkv + wbase + h * 32;
  const __bf16* kb = qb + 384;
  const bf16x8 z8 = {};
  const f32x4 fz = {};

  bf16x8 kf[7];
  #pragma unroll
  for (int ni = 0; ni < 7; ++ni) {
    int tok = ni * 16 + lr;
    kf[ni] = (tok < 98) ? *(const bf16x8*)(kb + (size_t)tok * QKV_DIM + lg * 8) : z8;
  }
  int qt = mi * 16 + lr;
  bf16x8 qf = (qt < 98) ? *(const bf16x8*)(qb + (size_t)qt * QKV_DIM + lg * 8) : z8;
  const f32x4* pbp = (const f32x4*)pb + (size_t)((h * 7 + mi) * 7) * 64 + l;
  f32x4 bv[7];
  #pragma unroll
  for (int ni = 0; ni < 7; ++ni) bv[ni] = pbp[ni * 64];

  f32x4 s[7];
  #pragma unroll
  for (int ni = 0; ni < 7; ++ni)
    s[ni] = __builtin_amdgcn_mfma_f32_16x16x32_bf16(qf, kf[ni], fz, 0, 0, 0);

  if (l < 32) {
    int row = l >> 1, c = 14 + (l & 1);
    *(f32x4*)(P + row * 256 + ((c ^ (row & 7)) << 4)) = fz;
  }

  #pragma unroll
  for (int r = 0; r < 4; ++r) {
    float mx = -1e30f;
    #pragma unroll
    for (int ni = 0; ni < 7; ++ni) {
      float vv = s[ni][r] + bv[ni][r];
      s[ni][r] = vv;
      mx = fmaxf(mx, vv);
    }
    #pragma unroll
    for (int m2 = 1; m2 < 16; m2 <<= 1) mx = fmaxf(mx, __shfl_xor(mx, m2, 64));
    float sum = 0.f;
    #pragma unroll
    for (int ni = 0; ni < 7; ++ni) { float p = __expf(s[ni][r] - mx); s[ni][r] = p; sum += p; }
    #pragma unroll
    for (int m2 = 1; m2 < 16; m2 <<= 1) sum += __shfl_xor(sum, m2, 64);
    float inv = 1.0f / sum;
    int il = lg * 4 + r;
    #pragma unroll
    for (int ni = 0; ni < 7; ++ni) {
      int j = ni * 16 + lr;
      *(__bf16*)(P + il * 256 + (((j >> 3) ^ (il & 7)) << 4) + ((j & 7) << 1)) =
          (__bf16)(s[ni][r] * inv);
    }
  }
  __syncthreads();

  bf16x8 pa[4];
  #pragma unroll
  for (int ks = 0; ks < 4; ++ks) {
    int ck = ks * 4 + lg;
    pa[ks] = *(const bf16x8*)(P + lr * 256 + ((ck ^ (lr & 7)) << 4));
  }
  const __bf16* vrow = vt + ((size_t)wh * 32) * 128;
  __bf16* ob = out + ((size_t)win * 98 + mi * 16) * DIM + h * 32;
  #pragma unroll
  for (int nf = 0; nf < 2; ++nf) {
    int d = nf * 16 + lr;
    f32x4 o = fz;
    #pragma unroll
    for (int ks = 0; ks < 4; ++ks) {
      bf16x8 vb = *(const bf16x8*)(vrow + (size_t)d * 128 + ks * 32 + lg * 8);
      o = __builtin_amdgcn_mfma_f32_16x16x32_bf16(pa[ks], vb, o, 0, 0, 0);
    }
    #pragma unroll
    for (int r = 0; r < 4; ++r) {
      int il = lg * 4 + r;
      if (mi * 16 + il < 98) ob[(size_t)il * DIM + nf * 16 + lr] = (__bf16)o[r];
    }
  }
}

// ---------------- launch ----------------
extern "C" void kernel_launch(void* const* d_in, const int* in_sizes, int n_in,
                              void* d_out, int out_size, void* d_ws, size_t ws_size,
                              hipStream_t stream) {
  const float* x      = (const float*)d_in[0];
  const float* n1g    = (const float*)d_in[1];
  const float* n1b    = (const float*)d_in[2];
  const float* qkv_w  = (const float*)d_in[3];
  const float* qkv_b  = (const float*)d_in[4];
  const float* proj_w = (const float*)d_in[5];
  const float* proj_b = (const float*)d_in[6];
  const float* btab   = (const float*)d_in[7];
  const float* n2g    = (const float*)d_in[8];
  const float* n2b    = (const float*)d_in[9];
  const float* fc1_w  = (const float*)d_in[10];
  const float* fc1_b  = (const float*)d_in[11];
  const float* fc2_w  = (const float*)d_in[12];
  const float* fc2_b  = (const float*)d_in[13];
  const int*   relidx = (const int*)d_in[14];
  float* outp = (float*)d_out;
  (void)in_sizes; (void)n_in; (void)out_size; (void)ws_size;

  char* ws = (char*)d_ws;
  size_t off = 0;
  auto alloc = [&](size_t bytes) {
    char* p = ws + off;
    off = (off + bytes + 255) & ~(size_t)255;
    return p;
  };
  int*    tokmap = (int*)alloc((size_t)NTOK * 4);
  float*  biasex = (float*)alloc((size_t)NHEADS * 49 * 256 * 4);
  __bf16* wqkvT  = (__bf16*)alloc((size_t)QKV_DIM * DIM * 2);
  __bf16* wprojT = (__bf16*)alloc((size_t)DIM * DIM * 2);
  __bf16* wfc1T  = (__bf16*)alloc((size_t)HID * DIM * 2);
  __bf16* wfc2T  = (__bf16*)alloc((size_t)DIM * HID * 2);
  float*  qkvbS  = (float*)alloc((size_t)QKV_DIM * 4);
  __bf16* tokens = (__bf16*)alloc((size_t)NTOK * DIM * 2);   // LN1 out / attn out / LN2 out
  __bf16* qkvbuf = (__bf16*)alloc((size_t)NTOK * HID * 2);   // qkv (1152) then h1 (1536)
  __bf16* attnout = tokens;
  __bf16* h1 = qkvbuf;
  // vt (50.3MB) lives in d_out (77MB fp32) — proj overwrites d_out afterwards
  __bf16* vt = (__bf16*)d_out;

  const float scale = 0.17677669529663687f;  // 1/sqrt(32)

  build_tokmap_k<<<NTOK / 256, 256, 0, stream>>>(tokmap);
  expand_biasp_k<<<(NHEADS * 49 * 256) / 256, 256, 0, stream>>>(btab, relidx, biasex);
  transpose_w_k<<<(DIM * QKV_DIM) / 256, 256, 0, stream>>>(qkv_w, wqkvT, DIM, QKV_DIM, DIM, scale);
  transpose_w_k<<<(DIM * DIM) / 256, 256, 0, stream>>>(proj_w, wprojT, DIM, DIM, 0, 1.0f);
  transpose_w_k<<<(DIM * HID) / 256, 256, 0, stream>>>(fc1_w, wfc1T, DIM, HID, 0, 1.0f);
  transpose_w_k<<<(HID * DIM) / 256, 256, 0, stream>>>(fc2_w, wfc2T, HID, DIM, 0, 1.0f);
  scale_bias_k<<<(QKV_DIM + 255) / 256, 256, 0, stream>>>(qkv_b, qkvbS, QKV_DIM, DIM, scale);

  ln_k<<<NTOK / 4, 256, 0, stream>>>(x, n1g, n1b, tokens, tokmap);
  gemm_k<0><<<(NTOK / 128) * (QKV_DIM / 128), 256, 0, stream>>>(
      tokens, wqkvT, qkvbS, NTOK, QKV_DIM, DIM, qkvbuf, nullptr, nullptr, nullptr);
  vtrans_k<<<NWIN, 384, 0, stream>>>(qkvbuf, vt);
  attn_k<<<NWIN * NHEADS * 7, 64, 0, stream>>>(qkvbuf, vt, biasex, attnout);
  gemm_k<1><<<(NTOK / 128) * (DIM / 128), 256, 0, stream>>>(
      attnout, wprojT, proj_b, NTOK, DIM, DIM, nullptr, outp, x, tokmap);
  ln_k<<<NTOK / 4, 256, 0, stream>>>(outp, n2g, n2b, tokens, nullptr);
  gemm_k<2><<<(NTOK / 128) * (HID / 128), 256, 0, stream>>>(
      tokens, wfc1T, fc1_b, NTOK, HID, DIM, h1, nullptr, nullptr, nullptr);
  gemm_k<3><<<(NTOK / 128) * (DIM / 128), 256, 0, stream>>>(
      h1, wfc2T, fc2_b, NTOK, DIM, HID, nullptr, outp, outp, nullptr);
}